// Round 11
// baseline (34.301 us; speedup 1.0000x reference)
//
#include <hip/hip_runtime.h>
#include <math.h>

#define BB 2
#define CC 16
#define HH 32
#define WW 32
#define NN (HH*WW)
#define NPX (BB*NN)        // 2048 pixels
#define NPG (NPX/64)       // 32 pixel-groups (64 px each)
#define SO  16             // outer k-splits (blocks per pixel-group)
#define KW  16             // k's per wave  (NN / SO / 4 waves)

// SoA arrays (soa4 = 9 x float4[NPX], soa2 = float2[NPX]):
//   [0..3] E0..E3 : embedding e[0..15]
//   [4]    Q0     : X, Y, Z, p0     (unprojected xyz; p*=pie(T_k x_k)+rev)
//   [5]    Q1     : p1, p2, w0, w1
//   [6..8] T0..T2 : rows of T_i  {R00,R01,R02,t0} etc.
//   soa2   Q2     : w2, |e|^2

// ---------------------------------------------------------------------------
// Kernel 1: per-(b,k) precompute into SoA (coalesced writes).
// ---------------------------------------------------------------------------
__global__ __launch_bounds__(64)
void dse3_prep7(const float* __restrict__ emb,
                const float* __restrict__ rev,
                const float* __restrict__ wgt,
                const float* __restrict__ dep,
                const float* __restrict__ pix,
                const float* __restrict__ Tm,
                float4* __restrict__ soa4,
                float2* __restrict__ soa2)
{
    int idx = blockIdx.x * 64 + threadIdx.x;
    if (idx >= NPX) return;
    int b = idx >> 10;
    int k = idx & (NN - 1);

    float fx = pix[b*16 + 0], fy = pix[b*16 + 5];
    float x0 = pix[b*16 + 2], y0 = pix[b*16 + 6];

    float u = (float)(k & (WW - 1));
    float v = (float)(k >> 5);
    float z = dep[b*NN + k];
    float X = (u - x0) * z / fx;
    float Y = (v - y0) * z / fy;

    const float* T = Tm + (size_t)idx * 16;
    float Tx = T[0]*X + T[1]*Y + T[2]*z  + T[3];
    float Ty = T[4]*X + T[5]*Y + T[6]*z  + T[7];
    float Tz = T[8]*X + T[9]*Y + T[10]*z + T[11];
    float di = 1.0f / Tz;

    float p0 = fx*Tx*di + x0 + rev[(size_t)b*3*NN + 0*NN + k];
    float p1 = fy*Ty*di + y0 + rev[(size_t)b*3*NN + 1*NN + k];
    float p2 = di            + rev[(size_t)b*3*NN + 2*NN + k];
    float w0 = wgt[(size_t)b*3*NN + 0*NN + k];
    float w1 = wgt[(size_t)b*3*NN + 1*NN + k];
    float w2 = wgt[(size_t)b*3*NN + 2*NN + k];

    float se = 0.f;
    float ev[16];
    #pragma unroll
    for (int c = 0; c < 16; ++c) {
        ev[c] = emb[(size_t)b*CC*NN + (size_t)c*NN + k];
        se += ev[c]*ev[c];
    }

    #pragma unroll
    for (int c4 = 0; c4 < 4; ++c4)
        soa4[(size_t)c4*NPX + idx] =
            make_float4(ev[c4*4+0], ev[c4*4+1], ev[c4*4+2], ev[c4*4+3]);
    soa4[(size_t)4*NPX + idx] = make_float4(X, Y, z, p0);
    soa4[(size_t)5*NPX + idx] = make_float4(p1, p2, w0, w1);
    soa4[(size_t)6*NPX + idx] = make_float4(T[0], T[1], T[2],  T[3]);
    soa4[(size_t)7*NPX + idx] = make_float4(T[4], T[5], T[6],  T[7]);
    soa4[(size_t)8*NPX + idx] = make_float4(T[8], T[9], T[10], T[11]);
    soa2[idx] = make_float2(w2, se);
}

// ---------------------------------------------------------------------------
// Kernel 2 (accum, TRANSPOSED mapping): lane = pixel, k broadcast.
// Block = 256 thr = 4 waves, all covering the same 64-pixel group;
// wave wv scans k's [o*64 + wv*16, +16). k-record loads are wave-uniform
// (1 cache line per load). 26 accumulators stay lane-private (no butterfly).
// LDS-combine the 4 waves; write partials pws[o][c][px] coalesced.
// ---------------------------------------------------------------------------
__global__ __launch_bounds__(256, 2)
void dse3_accum7(const float4* __restrict__ soa4,
                 const float2* __restrict__ soa2,
                 const float* __restrict__ pix,
                 float* __restrict__ pws)
{
    __shared__ float cls[4][64][27];   // stride 27: conflict-free
    int tid  = threadIdx.x;
    int lane = tid & 63;
    int wv   = tid >> 6;
    int pg   = blockIdx.x >> 4;        // pixel-group 0..31
    int o    = blockIdx.x & (SO - 1);  // outer k-split 0..15
    int b    = pg >> 4;                // 16 groups per batch
    int px   = pg*64 + lane;

    const float4* E0 = soa4;
    const float4* E1 = soa4 + (size_t)1*NPX;
    const float4* E2 = soa4 + (size_t)2*NPX;
    const float4* E3 = soa4 + (size_t)3*NPX;
    const float4* Q0 = soa4 + (size_t)4*NPX;
    const float4* Q1 = soa4 + (size_t)5*NPX;
    const float4* T0 = soa4 + (size_t)6*NPX;
    const float4* T1 = soa4 + (size_t)7*NPX;
    const float4* T2 = soa4 + (size_t)8*NPX;
    const float2* Q2 = soa2;

    // per-lane pixel data (coalesced float4 loads)
    float4 ei0 = E0[px], ei1 = E1[px], ei2 = E2[px], ei3 = E3[px];
    float  sei = Q2[px].y;
    float4 Tr0 = T0[px], Tr1 = T1[px], Tr2 = T2[px];
    float fx = pix[b*16 + 0], fy = pix[b*16 + 5];
    float x0 = pix[b*16 + 2], y0 = pix[b*16 + 6];

    float aM0=0.f, aM2=0.f, aM4=0.f, aM5=0.f, aM8=0.f;
    float aN0=0.f, aN1=0.f, aN2=0.f, aN3=0.f, aN4=0.f,
          aN5=0.f, aN6=0.f, aN7=0.f, aN8=0.f;
    float aP0=0.f, aP1=0.f, aP2=0.f, aP3=0.f, aP4=0.f, aP5=0.f;
    float aR0=0.f, aR1=0.f, aR2=0.f, aR3=0.f, aR4=0.f, aR5=0.f;

    int kbase = b*NN + o*64 + wv*KW;
    #pragma unroll 4
    for (int j = 0; j < KW; ++j) {
        int kb = kbase + j;            // wave-uniform address -> broadcast

        float4 ke0 = E0[kb], ke1 = E1[kb], ke2 = E2[kb], ke3 = E3[kb];
        float4 q0  = Q0[kb], q1  = Q1[kb];
        float2 q2  = Q2[kb];

        // affinity via Gram trick (e_i per lane, e_k broadcast)
        float d0 = ke0.x*ei0.x + ke0.y*ei0.y + ke0.z*ei0.z + ke0.w*ei0.w;
        float d1 = ke1.x*ei1.x + ke1.y*ei1.y + ke1.z*ei1.z + ke1.w*ei1.w;
        float d2 = ke2.x*ei2.x + ke2.y*ei2.y + ke2.z*ei2.z + ke2.w*ei2.w;
        float d3 = ke3.x*ei3.x + ke3.y*ei3.y + ke3.z*ei3.z + ke3.w*ei3.w;
        float dot = (d0 + d1) + (d2 + d3);
        float ssq = fmaxf(sei + q2.y - 2.f*dot, 0.f);
        float aff = __expf(-__builtin_amdgcn_sqrtf(ssq));

        float X = q0.x, Y = q0.y, Z = q0.z;
        float Tx = Tr0.x*X + Tr0.y*Y + Tr0.z*Z + Tr0.w;
        float Ty = Tr1.x*X + Tr1.y*Y + Tr1.z*Z + Tr1.w;
        float Tz = Tr2.x*X + Tr2.y*Y + Tr2.z*Z + Tr2.w;
        float di = __builtin_amdgcn_rcpf(Tz);

        float a =  fx*di;
        float e =  fy*di;
        float uu = a*Tx;
        float vv = e*Ty;
        float r0 = uu + x0 - q0.w;
        float r1 = vv + y0 - q1.x;
        float r2 = di      - q1.y;
        float c = -uu*di;
        float f = -vv*di;
        float g = -di*di;

        // rhs
        float y0v = a*r0;
        float y1v = e*r1;
        float y2v = c*r0 + f*r1 + g*r2;
        aR0 += y0v; aR1 += y1v; aR2 += y2v;
        aR3 += Z*y1v - Y*y2v;
        aR4 += X*y2v - Z*y0v;
        aR5 += Y*y0v - X*y1v;

        // M = Jp^T diag(aff*w) Jp  (M01 == 0)
        float w0 = aff*q1.z, w1 = aff*q1.w, w2 = aff*q2.x;
        float aw = w0*a, ew = w1*e;
        float m00 = aw*a, m02 = aw*c;
        float m11 = ew*e, m12 = ew*f;
        float m22 = w0*c*c + w1*f*f + w2*g*g;
        aM0 += m00; aM2 += m02; aM4 += m11; aM5 += m12; aM8 += m22;

        // N = M * hat(x_k)
        float n00 = -m02*Y;
        float n01 =  m02*X - m00*Z;
        float n02 =  m00*Y;
        float n10 =  m11*Z - m12*Y;
        float n11 =  m12*X;
        float n12 = -m11*X;
        float n20 =  m12*Z - m22*Y;
        float n21 =  m22*X - m02*Z;
        float n22 =  m02*Y - m12*X;
        aN0 += n00; aN1 += n01; aN2 += n02;
        aN3 += n10; aN4 += n11; aN5 += n12;
        aN6 += n20; aN7 += n21; aN8 += n22;

        // P = hat^T * N (symmetric)
        aP0 += Z*n10 - Y*n20;
        aP1 += Z*n11 - Y*n21;
        aP2 += Z*n12 - Y*n22;
        aP3 += X*n21 - Z*n01;
        aP4 += X*n22 - Z*n02;
        aP5 += Y*n02 - X*n12;
    }

    float acc[26] = { aM0,aM2,aM4,aM5,aM8,
                      aN0,aN1,aN2,aN3,aN4,aN5,aN6,aN7,aN8,
                      aP0,aP1,aP2,aP3,aP4,aP5,
                      aR0,aR1,aR2,aR3,aR4,aR5 };

    #pragma unroll
    for (int t = 0; t < 26; ++t) cls[wv][lane][t] = acc[t];
    __syncthreads();

    // combine 4 waves; write partials coalesced: pws[(o*26+c)*NPX + px]
    if (tid < 64) {
        #pragma unroll
        for (int t = 0; t < 26; ++t) {
            float s = cls[0][tid][t] + cls[1][tid][t]
                    + cls[2][tid][t] + cls[3][tid][t];
            pws[(size_t)(o*26 + t)*NPX + pg*64 + tid] = s;
        }
    }
}

// ---------------------------------------------------------------------------
// Kernel 3: one thread per pixel. Sum 16 partials (coalesced), f32 Cholesky
// (rcp-based), expmap, compose. Fully lane-parallel.
// ---------------------------------------------------------------------------
__global__ __launch_bounds__(64)
void dse3_solve7(const float* __restrict__ pws,
                 const float4* __restrict__ soa4,
                 const float* __restrict__ Tm,
                 float* __restrict__ out)
{
    int px = blockIdx.x * 64 + threadIdx.x;
    if (px >= NPX) return;

    float hv[26];
    #pragma unroll
    for (int t = 0; t < 26; ++t) hv[t] = 0.f;
    #pragma unroll
    for (int o = 0; o < SO; ++o)
        #pragma unroll
        for (int t = 0; t < 26; ++t)
            hv[t] += pws[(size_t)(o*26 + t)*NPX + px];

    float am[6][6];
    am[0][0]=hv[0]; am[0][1]=0.f;   am[0][2]=hv[1];
    am[1][1]=hv[2]; am[1][2]=hv[3]; am[2][2]=hv[4];
    am[0][3]=hv[5];  am[0][4]=hv[6];  am[0][5]=hv[7];
    am[1][3]=hv[8];  am[1][4]=hv[9];  am[1][5]=hv[10];
    am[2][3]=hv[11]; am[2][4]=hv[12]; am[2][5]=hv[13];
    am[3][3]=hv[14]; am[3][4]=hv[15]; am[3][5]=hv[16];
    am[4][4]=hv[17]; am[4][5]=hv[18]; am[5][5]=hv[19];
    #pragma unroll
    for (int p = 0; p < 6; ++p)
        #pragma unroll
        for (int q = 0; q < p; ++q) am[p][q] = am[q][p];
    float rh[6] = { hv[20], hv[21], hv[22], hv[23], hv[24], hv[25] };

    // f32 Cholesky with reciprocal diagonal
    float L[6][6], dinv[6];
    #pragma unroll
    for (int p = 0; p < 6; ++p) {
        #pragma unroll
        for (int q = 0; q <= p; ++q) {
            float sm = am[p][q];
            #pragma unroll
            for (int r = 0; r < q; ++r) sm -= L[p][r]*L[q][r];
            if (q == p) {
                float s = __builtin_amdgcn_sqrtf(sm);
                L[p][p] = s;
                dinv[p] = __builtin_amdgcn_rcpf(s);
            } else {
                L[p][q] = sm * dinv[q];
            }
        }
    }
    float yv[6];
    #pragma unroll
    for (int p = 0; p < 6; ++p) {
        float sm = rh[p];
        #pragma unroll
        for (int r = 0; r < p; ++r) sm -= L[p][r]*yv[r];
        yv[p] = sm * dinv[p];
    }
    float sol[6];
    #pragma unroll
    for (int pi = 5; pi >= 0; --pi) {
        float sm = yv[pi];
        #pragma unroll
        for (int r = pi + 1; r < 6; ++r) sm -= L[r][pi]*sol[r];
        sol[pi] = sm * dinv[pi];
    }

    // expmap(delta)
    float vx = sol[0], vy = sol[1], vz = sol[2];
    float wx = sol[3], wy = sol[4], wz = sol[5];
    float th2 = wx*wx + wy*wy + wz*wz;
    float th  = __builtin_amdgcn_sqrtf(th2);
    float Ae, Be, Ce;
    if (th < 1e-4f) {
        Ae = 1.0f - th2*(1.0f/6.0f);
        Be = 0.5f - th2*(1.0f/24.0f);
        Ce = 1.0f/6.0f - th2*(1.0f/120.0f);
    } else {
        float sn = __sinf(th), cn = __cosf(th);
        float ith = __builtin_amdgcn_rcpf(th), ith2 = ith*ith;
        Ae = sn*ith;
        Be = (1.0f - cn)*ith2;
        Ce = (th - sn)*ith2*ith;
    }
    float Wh[3][3] = {{0.f,-wz, wy},{ wz,0.f,-wx},{-wy, wx,0.f}};
    float W2[3][3] = {{wx*wx - th2, wx*wy,       wx*wz      },
                      {wx*wy,       wy*wy - th2, wy*wz      },
                      {wx*wz,       wy*wz,       wz*wz - th2}};
    float Rd[3][3], Vd[3][3];
    #pragma unroll
    for (int p = 0; p < 3; ++p)
        #pragma unroll
        for (int q = 0; q < 3; ++q) {
            float idq = (p == q) ? 1.0f : 0.0f;
            Rd[p][q] = idq + Ae*Wh[p][q] + Be*W2[p][q];
            Vd[p][q] = idq + Be*Wh[p][q] + Ce*W2[p][q];
        }
    float td[3];
    #pragma unroll
    for (int p = 0; p < 3; ++p)
        td[p] = Vd[p][0]*vx + Vd[p][1]*vy + Vd[p][2]*vz;

    // compose: rows of T_i from SoA (coalesced), bottom row from Tm
    const float4* T0 = soa4 + (size_t)6*NPX;
    const float4* T1 = soa4 + (size_t)7*NPX;
    const float4* T2 = soa4 + (size_t)8*NPX;
    float4 Tr[3] = { T0[px], T1[px], T2[px] };
    const float4 bot = *(const float4*)(Tm + (size_t)px*16 + 12);

    float* o = out + (size_t)px * 16;
    #pragma unroll
    for (int p = 0; p < 3; ++p) {
        float4 r;
        r.x = Rd[p][0]*Tr[0].x + Rd[p][1]*Tr[1].x + Rd[p][2]*Tr[2].x + td[p]*bot.x;
        r.y = Rd[p][0]*Tr[0].y + Rd[p][1]*Tr[1].y + Rd[p][2]*Tr[2].y + td[p]*bot.y;
        r.z = Rd[p][0]*Tr[0].z + Rd[p][1]*Tr[1].z + Rd[p][2]*Tr[2].z + td[p]*bot.z;
        r.w = Rd[p][0]*Tr[0].w + Rd[p][1]*Tr[1].w + Rd[p][2]*Tr[2].w + td[p]*bot.w;
        *(float4*)(o + p*4) = r;
    }
    *(float4*)(o + 12) = bot;
}

extern "C" void kernel_launch(void* const* d_in, const int* in_sizes, int n_in,
                              void* d_out, int out_size, void* d_ws, size_t ws_size,
                              hipStream_t stream) {
    const float* emb = (const float*)d_in[0];  // (B,C,H,W)
    const float* rev = (const float*)d_in[1];  // (B,3,H,W)
    const float* wgt = (const float*)d_in[2];  // (B,3,H,W)
    const float* dep = (const float*)d_in[3];  // (B,1,H,W)
    const float* pix = (const float*)d_in[4];  // (B,4,4)
    const float* Tm  = (const float*)d_in[5];  // (B,H,W,4,4)
    float* out = (float*)d_out;                // (B,H,W,4,4)

    float4* soa4 = (float4*)d_ws;                      // 9*NPX float4 = 288 KB
    float2* soa2 = (float2*)(soa4 + (size_t)9*NPX);    // NPX float2   =  16 KB
    float*  pws  = (float*)(soa2 + (size_t)NPX);       // 16*26*NPX f32 = 3.4 MB

    dse3_prep7 <<<NPX/64, 64, 0, stream>>>(emb, rev, wgt, dep, pix, Tm, soa4, soa2);
    dse3_accum7<<<NPG*SO, 256, 0, stream>>>(soa4, soa2, pix, pws);
    dse3_solve7<<<NPX/64, 64, 0, stream>>>(pws, soa4, Tm, out);
}

// Round 13
// 23.752 us; speedup vs baseline: 1.4442x; 1.4442x over previous
//
#include <hip/hip_runtime.h>
#include <math.h>

#define BB 2
#define CC 16
#define HH 32
#define WW 32
#define NN (HH*WW)
#define NPX (BB*NN)        // 2048 pixels
#define PH  512            // k-records per LDS phase

// ---------------------------------------------------------------------------
// Single kernel: 512 blocks x 256 thr (4 waves). Block owns 4 pixels (one per
// wave), all in the same batch. Two LDS phases of 512 k-records each:
//   fill (redundant per-block prep, coalesced global reads, linear LDS writes)
//   -> sync -> each wave accumulates its pixel over the 512 records
//   (conflict-free linear ds_read_b128) -> sync -> next phase.
// Then 64-lane butterfly (complete H per wave) and lane-0 f32 solve+compose.
// ---------------------------------------------------------------------------
__global__ __launch_bounds__(256, 2)
void dse3_mono(const float* __restrict__ emb,
               const float* __restrict__ rev,
               const float* __restrict__ wgt,
               const float* __restrict__ dep,
               const float* __restrict__ pix,
               const float* __restrict__ Tm,
               float* __restrict__ out)
{
    __shared__ float4 sE0[PH], sE1[PH], sE2[PH], sE3[PH], sQ0[PH], sQ1[PH];
    __shared__ float2 sQ2[PH];          // 53.2 KB total

    int tid  = threadIdx.x;
    int lane = tid & 63;
    int wv   = tid >> 6;
    int px   = blockIdx.x * 4 + wv;     // this wave's pixel
    int b    = px >> 10;
    int kpx  = px & (NN - 1);

    float fx = pix[b*16 + 0], fy = pix[b*16 + 5];
    float x0 = pix[b*16 + 2], y0 = pix[b*16 + 6];
    float ifx = __builtin_amdgcn_rcpf(fx);
    float ify = __builtin_amdgcn_rcpf(fy);

    // ---- this wave's pixel data (wave-uniform loads) ----
    float ei[16];
    float sei = 0.f;
    #pragma unroll
    for (int c = 0; c < 16; ++c) {
        ei[c] = emb[(size_t)b*CC*NN + (size_t)c*NN + kpx];
        sei += ei[c]*ei[c];
    }
    const float4* Tp4 = (const float4*)(Tm + (size_t)px * 16);
    float4 Tr0 = Tp4[0], Tr1 = Tp4[1], Tr2 = Tp4[2];

    // ---- accumulators (M-factorized, 26) ----
    float aM0=0.f, aM2=0.f, aM4=0.f, aM5=0.f, aM8=0.f;
    float aN0=0.f, aN1=0.f, aN2=0.f, aN3=0.f, aN4=0.f,
          aN5=0.f, aN6=0.f, aN7=0.f, aN8=0.f;
    float aP0=0.f, aP1=0.f, aP2=0.f, aP3=0.f, aP4=0.f, aP5=0.f;
    float aR0=0.f, aR1=0.f, aR2=0.f, aR3=0.f, aR4=0.f, aR5=0.f;

    #pragma unroll
    for (int phase = 0; phase < 2; ++phase) {
        // ================= fill: 512 records, 2 per thread =================
        #pragma unroll
        for (int rr = 0; rr < 2; ++rr) {
            int r  = rr*256 + tid;
            int k  = phase*PH + r;
            int gk = b*NN + k;

            float se = 0.f;
            float ev[16];
            #pragma unroll
            for (int c = 0; c < 16; ++c) {
                ev[c] = emb[(size_t)b*CC*NN + (size_t)c*NN + k];
                se += ev[c]*ev[c];
            }
            float u = (float)(k & (WW - 1));
            float v = (float)((k & (NN-1)) >> 5);
            float z = dep[b*NN + k];
            float X = (u - x0) * z * ifx;
            float Y = (v - y0) * z * ify;

            const float4* T4 = (const float4*)(Tm + (size_t)gk * 16);
            float4 t0 = T4[0], t1 = T4[1], t2 = T4[2];
            float Tx = t0.x*X + t0.y*Y + t0.z*z + t0.w;
            float Ty = t1.x*X + t1.y*Y + t1.z*z + t1.w;
            float Tz = t2.x*X + t2.y*Y + t2.z*z + t2.w;
            float di = __builtin_amdgcn_rcpf(Tz);

            float p0 = fx*Tx*di + x0 + rev[(size_t)b*3*NN + 0*NN + k];
            float p1 = fy*Ty*di + y0 + rev[(size_t)b*3*NN + 1*NN + k];
            float p2 = di            + rev[(size_t)b*3*NN + 2*NN + k];
            float w0 = wgt[(size_t)b*3*NN + 0*NN + k];
            float w1 = wgt[(size_t)b*3*NN + 1*NN + k];
            float w2 = wgt[(size_t)b*3*NN + 2*NN + k];

            sE0[r] = make_float4(ev[0],  ev[1],  ev[2],  ev[3]);
            sE1[r] = make_float4(ev[4],  ev[5],  ev[6],  ev[7]);
            sE2[r] = make_float4(ev[8],  ev[9],  ev[10], ev[11]);
            sE3[r] = make_float4(ev[12], ev[13], ev[14], ev[15]);
            sQ0[r] = make_float4(X, Y, z, p0);
            sQ1[r] = make_float4(p1, p2, w0, w1);
            sQ2[r] = make_float2(w2, se);
        }
        __syncthreads();

        // ================= accum: 8 iters x 64 lanes =================
        #pragma unroll 2
        for (int j = 0; j < 8; ++j) {
            int r = j*64 + lane;

            float4 k0 = sE0[r], k1 = sE1[r], k2 = sE2[r], k3 = sE3[r];
            float4 q0 = sQ0[r], q1 = sQ1[r];
            float2 q2 = sQ2[r];

            float d0 = k0.x*ei[0]  + k0.y*ei[1]  + k0.z*ei[2]  + k0.w*ei[3];
            float d1 = k1.x*ei[4]  + k1.y*ei[5]  + k1.z*ei[6]  + k1.w*ei[7];
            float d2 = k2.x*ei[8]  + k2.y*ei[9]  + k2.z*ei[10] + k2.w*ei[11];
            float d3 = k3.x*ei[12] + k3.y*ei[13] + k3.z*ei[14] + k3.w*ei[15];
            float dot = (d0 + d1) + (d2 + d3);
            float ssq = fmaxf(sei + q2.y - 2.f*dot, 0.f);
            float aff = __expf(-__builtin_amdgcn_sqrtf(ssq));

            float X = q0.x, Y = q0.y, Z = q0.z;
            float Tx = Tr0.x*X + Tr0.y*Y + Tr0.z*Z + Tr0.w;
            float Ty = Tr1.x*X + Tr1.y*Y + Tr1.z*Z + Tr1.w;
            float Tz = Tr2.x*X + Tr2.y*Y + Tr2.z*Z + Tr2.w;
            float di = __builtin_amdgcn_rcpf(Tz);

            float a =  fx*di;
            float e =  fy*di;
            float uu = a*Tx;
            float vv = e*Ty;
            float r0 = uu + x0 - q0.w;
            float r1 = vv + y0 - q1.x;
            float r2 = di      - q1.y;
            float c = -uu*di;
            float f = -vv*di;
            float g = -di*di;

            float y0v = a*r0;
            float y1v = e*r1;
            float y2v = c*r0 + f*r1 + g*r2;
            aR0 += y0v; aR1 += y1v; aR2 += y2v;
            aR3 += Z*y1v - Y*y2v;
            aR4 += X*y2v - Z*y0v;
            aR5 += Y*y0v - X*y1v;

            float w0 = aff*q1.z, w1 = aff*q1.w, w2 = aff*q2.x;
            float aw = w0*a, ew = w1*e;
            float m00 = aw*a, m02 = aw*c;
            float m11 = ew*e, m12 = ew*f;
            float m22 = w0*c*c + w1*f*f + w2*g*g;
            aM0 += m00; aM2 += m02; aM4 += m11; aM5 += m12; aM8 += m22;

            float n00 = -m02*Y;
            float n01 =  m02*X - m00*Z;
            float n02 =  m00*Y;
            float n10 =  m11*Z - m12*Y;
            float n11 =  m12*X;
            float n12 = -m11*X;
            float n20 =  m12*Z - m22*Y;
            float n21 =  m22*X - m02*Z;
            float n22 =  m02*Y - m12*X;
            aN0 += n00; aN1 += n01; aN2 += n02;
            aN3 += n10; aN4 += n11; aN5 += n12;
            aN6 += n20; aN7 += n21; aN8 += n22;

            aP0 += Z*n10 - Y*n20;
            aP1 += Z*n11 - Y*n21;
            aP2 += Z*n12 - Y*n22;
            aP3 += X*n21 - Z*n01;
            aP4 += X*n22 - Z*n02;
            aP5 += Y*n02 - X*n12;
        }
        __syncthreads();   // protect LDS before next fill
    }

    // ================= butterfly reduce (26) =================
    float acc[26] = { aM0,aM2,aM4,aM5,aM8,
                      aN0,aN1,aN2,aN3,aN4,aN5,aN6,aN7,aN8,
                      aP0,aP1,aP2,aP3,aP4,aP5,
                      aR0,aR1,aR2,aR3,aR4,aR5 };
    #pragma unroll
    for (int off = 32; off > 0; off >>= 1)
        #pragma unroll
        for (int t = 0; t < 26; ++t)
            acc[t] += __shfl_xor(acc[t], off, 64);

    if (lane != 0) return;

    // ================= lane-0 solve (f32) + expmap + compose =================
    float am[6][6];
    am[0][0]=acc[0]; am[0][1]=0.f;    am[0][2]=acc[1];
    am[1][1]=acc[2]; am[1][2]=acc[3]; am[2][2]=acc[4];
    am[0][3]=acc[5];  am[0][4]=acc[6];  am[0][5]=acc[7];
    am[1][3]=acc[8];  am[1][4]=acc[9];  am[1][5]=acc[10];
    am[2][3]=acc[11]; am[2][4]=acc[12]; am[2][5]=acc[13];
    am[3][3]=acc[14]; am[3][4]=acc[15]; am[3][5]=acc[16];
    am[4][4]=acc[17]; am[4][5]=acc[18]; am[5][5]=acc[19];
    #pragma unroll
    for (int p = 0; p < 6; ++p)
        #pragma unroll
        for (int q = 0; q < p; ++q) am[p][q] = am[q][p];
    float rh[6] = { acc[20], acc[21], acc[22], acc[23], acc[24], acc[25] };

    float L[6][6], dinv[6];
    #pragma unroll
    for (int p = 0; p < 6; ++p) {
        #pragma unroll
        for (int q = 0; q <= p; ++q) {
            float sm = am[p][q];
            #pragma unroll
            for (int r = 0; r < q; ++r) sm -= L[p][r]*L[q][r];
            if (q == p) {
                float sq = __builtin_amdgcn_sqrtf(sm);
                L[p][p] = sq;
                dinv[p] = __builtin_amdgcn_rcpf(sq);
            } else {
                L[p][q] = sm * dinv[q];
            }
        }
    }
    float yv[6];
    #pragma unroll
    for (int p = 0; p < 6; ++p) {
        float sm = rh[p];
        #pragma unroll
        for (int r = 0; r < p; ++r) sm -= L[p][r]*yv[r];
        yv[p] = sm * dinv[p];
    }
    float sol[6];
    #pragma unroll
    for (int pi = 5; pi >= 0; --pi) {
        float sm = yv[pi];
        #pragma unroll
        for (int r = pi + 1; r < 6; ++r) sm -= L[r][pi]*sol[r];
        sol[pi] = sm * dinv[pi];
    }

    float vx = sol[0], vy = sol[1], vz = sol[2];
    float wx = sol[3], wy = sol[4], wz = sol[5];
    float th2 = wx*wx + wy*wy + wz*wz;
    float th  = __builtin_amdgcn_sqrtf(th2);
    float Ae, Be, Ce;
    if (th < 1e-4f) {
        Ae = 1.0f - th2*(1.0f/6.0f);
        Be = 0.5f - th2*(1.0f/24.0f);
        Ce = 1.0f/6.0f - th2*(1.0f/120.0f);
    } else {
        float sn = __sinf(th), cn = __cosf(th);
        float ith = __builtin_amdgcn_rcpf(th), ith2 = ith*ith;
        Ae = sn*ith;
        Be = (1.0f - cn)*ith2;
        Ce = (th - sn)*ith2*ith;
    }
    float Wh[3][3] = {{0.f,-wz, wy},{ wz,0.f,-wx},{-wy, wx,0.f}};
    float W2[3][3] = {{wx*wx - th2, wx*wy,       wx*wz      },
                      {wx*wy,       wy*wy - th2, wy*wz      },
                      {wx*wz,       wy*wz,       wz*wz - th2}};
    float Rd[3][3], Vd[3][3];
    #pragma unroll
    for (int p = 0; p < 3; ++p)
        #pragma unroll
        for (int q = 0; q < 3; ++q) {
            float idq = (p == q) ? 1.0f : 0.0f;
            Rd[p][q] = idq + Ae*Wh[p][q] + Be*W2[p][q];
            Vd[p][q] = idq + Be*Wh[p][q] + Ce*W2[p][q];
        }
    float td[3];
    #pragma unroll
    for (int p = 0; p < 3; ++p)
        td[p] = Vd[p][0]*vx + Vd[p][1]*vy + Vd[p][2]*vz;

    const float4 bot = Tp4[3];
    float* o = out + (size_t)px * 16;
    #pragma unroll
    for (int p = 0; p < 3; ++p) {
        float4 r;
        float4 Ta = (p==0)?Tr0:((p==1)?Tr1:Tr2);  (void)Ta;
        r.x = Rd[p][0]*Tr0.x + Rd[p][1]*Tr1.x + Rd[p][2]*Tr2.x + td[p]*bot.x;
        r.y = Rd[p][0]*Tr0.y + Rd[p][1]*Tr1.y + Rd[p][2]*Tr2.y + td[p]*bot.y;
        r.z = Rd[p][0]*Tr0.z + Rd[p][1]*Tr1.z + Rd[p][2]*Tr2.z + td[p]*bot.z;
        r.w = Rd[p][0]*Tr0.w + Rd[p][1]*Tr1.w + Rd[p][2]*Tr2.w + td[p]*bot.w;
        *(float4*)(o + p*4) = r;
    }
    *(float4*)(o + 12) = bot;
}

extern "C" void kernel_launch(void* const* d_in, const int* in_sizes, int n_in,
                              void* d_out, int out_size, void* d_ws, size_t ws_size,
                              hipStream_t stream) {
    const float* emb = (const float*)d_in[0];  // (B,C,H,W)
    const float* rev = (const float*)d_in[1];  // (B,3,H,W)
    const float* wgt = (const float*)d_in[2];  // (B,3,H,W)
    const float* dep = (const float*)d_in[3];  // (B,1,H,W)
    const float* pix = (const float*)d_in[4];  // (B,4,4)
    const float* Tm  = (const float*)d_in[5];  // (B,H,W,4,4)
    float* out = (float*)d_out;                // (B,H,W,4,4)

    dse3_mono<<<NPX/4, 256, 0, stream>>>(emb, rev, wgt, dep, pix, Tm, out);
}